// Round 10
// baseline (234.341 us; speedup 1.0000x reference)
//
#include <hip/hip_runtime.h>
#include <hip/hip_bf16.h>
#include <hip/hip_fp16.h>
#include <stdint.h>

typedef __bf16 bf16_t;
typedef bf16_t bf16x8 __attribute__((ext_vector_type(8)));
typedef bf16_t bf16x4 __attribute__((ext_vector_type(4)));
typedef float f32x4 __attribute__((ext_vector_type(4)));

#define BM 128
#define BN 128
#define BK 64

// async global->LDS, 16B per lane. LDS dst is wave-uniform base + lane*16;
// the GLOBAL source may be arbitrary per-lane (used for the bank swizzle).
__device__ __forceinline__ void gload_lds16(const void* g, void* l) {
    __builtin_amdgcn_global_load_lds(
        (const __attribute__((address_space(1))) void*)(uintptr_t)g,
        (__attribute__((address_space(3))) void*)(uintptr_t)l,
        16, 0, 0);
}

// ---------------------------------------------------------------------------
// 128x128 body, BK=64 as TWO stacked BK=32 sub-tiles (r5: conflicts 4.3M->0).
// Each half uses the verified BK=32 swizzle: staging slot s of row r holds
// global chunk ((s-(r>>1))&3) (compensated on the per-lane global source),
// read at phys chunk ((hw+(r>>1))&3).
// EPI: 0 = plain bf16 row-major store           (gemm1 K|Q)
//      2 = f32 store / rs[row]                  (gemm3)
//      3 = exp+causal bf16 store + atomic row-sum into rs  (qk)
//      4 = bf16 transposed into Vt[b][d][s]     (gemm1 V)
// CLOSED BRANCHES (do not revisit):
//  r6: per-tile agent fences -> L2 invalidation storm (FETCH 344 MB, 922 us)
//  r8: coop + __launch_bounds__(256,4) -> VGPR=64 spill storm (560 us)
//  r9: coop + free VGPR (132) -> co-residency caps TLP + grid-stride kills
//      XCD L2 locality (FETCH 151 MB, Occ 11.9%, 387 us)
//  => 4-dispatch structure is the measured optimum for this decomposition.
// ---------------------------------------------------------------------------
template <int EPI>
__device__ __forceinline__ void gemm_body(
    bf16_t* __restrict__ As, bf16_t* __restrict__ Bs,
    const bf16_t* __restrict__ A, long lda,
    const bf16_t* __restrict__ B, long ldb,
    void* __restrict__ Cv, long ldc,
    int k0beg, int k1end, float scale, int m0, int n0,
    float* __restrict__ rs)
{
    const int tid = threadIdx.x;
    const int wid = tid >> 6, lane = tid & 63;
    const int wr = wid >> 1, wc = wid & 1;
    const int hw = lane >> 4, ln = lane & 15;

    const int row0 = tid >> 2;                       // 0..63
    const int jj = ((tid & 3) - (tid >> 3)) & 3;     // swizzle-compensated chunk
    const bf16_t* srcA0 = A + (size_t)(m0 + row0) * lda + jj * 8;
    const bf16_t* srcB0 = B + (size_t)(n0 + row0) * ldb + jj * 8;

    f32x4 acc[4][4] = {};

    for (int k0 = k0beg; k0 < k1end; k0 += BK) {
#pragma unroll
        for (int i = 0; i < 4; i++) {
            const size_t roff = (size_t)((i & 1) * 64);
            const int koff = k0 + (i >> 1) * 32;
            gload_lds16(srcA0 + roff * lda + koff, &As[i * 2048 + tid * 8]);
            gload_lds16(srcB0 + roff * ldb + koff, &Bs[i * 2048 + tid * 8]);
        }
        __syncthreads();

#pragma unroll
        for (int h = 0; h < 2; h++) {
            bf16x8 af[4], bfr[4];
#pragma unroll
            for (int t = 0; t < 4; t++) {
                const int r  = wr * 64 + t * 16 + ln;
                const int rb = wc * 64 + t * 16 + ln;
                af[t]  = *(const bf16x8*)&As[h * 4096 + r  * 32 + (((hw + (r  >> 1)) & 3) * 8)];
                bfr[t] = *(const bf16x8*)&Bs[h * 4096 + rb * 32 + (((hw + (rb >> 1)) & 3) * 8)];
            }
#pragma unroll
            for (int ti = 0; ti < 4; ti++)
#pragma unroll
                for (int tj = 0; tj < 4; tj++)
                    acc[ti][tj] = __builtin_amdgcn_mfma_f32_16x16x32_bf16(
                        af[ti], bfr[tj], acc[ti][tj], 0, 0, 0);
        }
        __syncthreads();
    }

    // epilogue: C/D layout col=lane&15, row=(lane>>4)*4+reg (m89-verified)
#pragma unroll
    for (int ti = 0; ti < 4; ti++) {
        const int rbase = m0 + wr * 64 + ti * 16 + hw * 4;
        f32x4 inv4;
        if (EPI == 2) {
            const float4 r4 = *(const float4*)&rs[rbase];
            inv4[0] = 1.0f / r4.x; inv4[1] = 1.0f / r4.y;
            inv4[2] = 1.0f / r4.z; inv4[3] = 1.0f / r4.w;
        }
        float part[4] = {0.f, 0.f, 0.f, 0.f};
#pragma unroll
        for (int tj = 0; tj < 4; tj++) {
            const int col = n0 + wc * 64 + tj * 16 + ln;
            if (EPI == 4) {
                // transposed bf16: 4 consecutive rows -> 8B contiguous in Vt
                const int bb = rbase >> 11;
                const int s  = rbase & 2047;
                const int d  = col - 2048;
                bf16x4 o;
#pragma unroll
                for (int rg = 0; rg < 4; rg++) o[rg] = (bf16_t)acc[ti][tj][rg];
                *(bf16x4*)&((bf16_t*)Cv)[(size_t)bb * 2097152 + (size_t)d * 2048 + s] = o;
            } else {
#pragma unroll
                for (int rg = 0; rg < 4; rg++) {
                    const size_t idx = (size_t)(rbase + rg) * ldc + col;
                    if (EPI == 0) {
                        ((bf16_t*)Cv)[idx] = (bf16_t)acc[ti][tj][rg];
                    } else if (EPI == 2) {
                        ((float*)Cv)[idx] = acc[ti][tj][rg] * inv4[rg];
                    } else {  // EPI 3: exp + causal mask + row-sum
                        const float e = (col <= rbase + rg)
                                      ? __expf(acc[ti][tj][rg] * scale) : 0.0f;
                        part[rg] += e;
                        ((bf16_t*)Cv)[idx] = (bf16_t)e;
                    }
                }
            }
        }
        if (EPI == 3) {
#pragma unroll
            for (int rg = 0; rg < 4; rg++) {
                float p = part[rg];
                p += __shfl_xor(p, 1, 64);
                p += __shfl_xor(p, 2, 64);
                p += __shfl_xor(p, 4, 64);
                p += __shfl_xor(p, 8, 64);
                if (ln == 0) atomicAdd(&rs[rbase + rg], p);
            }
        }
    }
}

// ------------------------- shared tile-mapping helpers ---------------------
__device__ __forceinline__ void kq_tile(int g, int& m0, int& n0) {
    // 1024 tiles = 64 mblk x 16 nblk; XCD-pinned: xcd owns mblk [8x,8x+8),
    // per-phase footprint 2+2 MB = one XCD L2.
    const int xcd = g & 7;
    const int j   = g >> 3;
    const int p   = j >> 6;                // 0..1
    const int w   = j & 63;
    m0 = (xcd * 8 + (w >> 3)) * BM;
    n0 = (p * 8 + (w & 7)) * BN;
}

__device__ __forceinline__ void qk_tile(int q, int& b, int& my, int& nx) {
    b = q & 3;
    int rem = q >> 2;                      // 0..135
    my = 15; nx = 0;
#pragma unroll
    for (int m = 15; m >= 0; --m) {        // heavy strips first
        if (rem < m + 1) { my = m; nx = rem; break; }
        rem -= m + 1;
    }
}

// ---------------------------------------------------------------------------
// Kernel 1: merged input casts. blocks [0,8192) cast x, [8192,11264) cast W,
// [11264,11272) zero the rowsum array (4x2048 f32).
// ---------------------------------------------------------------------------
__global__ __launch_bounds__(256) void cast_all(
    const float* __restrict__ x,
    const float* __restrict__ Wk, const float* __restrict__ Wq,
    const float* __restrict__ Wv,
    bf16_t* __restrict__ xb, bf16_t* __restrict__ Wb,
    float* __restrict__ rowsum)
{
    const int blk = blockIdx.x;
    if (blk >= 11264) {
        const size_t i = ((size_t)(blk - 11264) * 256 + threadIdx.x) * 4;
        *(float4*)(rowsum + i) = make_float4(0.f, 0.f, 0.f, 0.f);
        return;
    }
    const float* src;
    bf16_t* dst;
    if (blk < 8192) {
        const size_t i = ((size_t)blk * 256 + threadIdx.x) * 4;
        src = x + i;
        dst = xb + i;
    } else {
        const size_t j = ((size_t)(blk - 8192) * 256 + threadIdx.x) * 4;
        dst = Wb + j;
        if (j < (size_t)1048576)      src = Wk + j;
        else if (j < (size_t)2097152) src = Wq + (j - 1048576);
        else                          src = Wv + (j - 2097152);
    }
    const float4 v = *(const float4*)src;
    bf16x4 o;
    o.x = (bf16_t)v.x; o.y = (bf16_t)v.y; o.z = (bf16_t)v.z; o.w = (bf16_t)v.w;
    *(bf16x4*)dst = o;
}

// ---------------------------------------------------------------------------
// Kernel 2: [K|Q] = x*W^T into QKVb (8192x2048). 1024 blocks, XCD-pinned.
// ---------------------------------------------------------------------------
__global__ __launch_bounds__(256) void gemm1_kq128(
    const bf16_t* __restrict__ xb, const bf16_t* __restrict__ Wb,
    bf16_t* __restrict__ QKVb)
{
    __shared__ __align__(16) bf16_t As[BM * BK];
    __shared__ __align__(16) bf16_t Bs[BN * BK];
    int m0, n0;
    kq_tile(blockIdx.x, m0, n0);
    gemm_body<0>(As, Bs, xb, 1024, Wb, 1024, QKVb, 2048,
                 0, 1024, 1.0f, m0, n0, nullptr);
}

// ---------------------------------------------------------------------------
// Kernel 3: FUSED V-projection + QK-exp (independent once kq is done).
// ids [0,512)=V transposed into Vt; [512,1056)=QK heavy-first.
// ---------------------------------------------------------------------------
__global__ __launch_bounds__(256) void vqk_fused(
    const bf16_t* __restrict__ xb, const bf16_t* __restrict__ Wb,
    bf16_t* __restrict__ Vt,
    const bf16_t* __restrict__ QKVb, bf16_t* __restrict__ E,
    float* __restrict__ rowsum)
{
    __shared__ __align__(16) bf16_t As[BM * BK];
    __shared__ __align__(16) bf16_t Bs[BN * BK];
    const int id = blockIdx.x;
    if (id < 512) {
        const int xcd = id & 7;
        const int j   = id >> 3;               // 0..63
        const int mblk = xcd * 8 + (j >> 3);   // 0..63
        const int nblk = j & 7;                // 0..7
        gemm_body<4>(As, Bs, xb, 1024, Wb, 1024, Vt, 2048,
                     0, 1024, 1.0f, mblk * BM, 2048 + nblk * BN, nullptr);
    } else {
        int b, my, nx;
        qk_tile(id - 512, b, my, nx);
        const bf16_t* base = QKVb + (size_t)b * (2048L * 2048);
        gemm_body<3>(As, Bs,
                     base + 1024, 2048,        // Q
                     base, 2048,               // K
                     E + (size_t)b * (2048L * 2048), 2048,
                     0, 1024, 0.03125f, my * BM, nx * BN,
                     rowsum + b * 2048);
    }
}

// --------------------- serial pair (small-ws fallback) ---------------------
__global__ __launch_bounds__(256) void gemm1_v(
    const bf16_t* __restrict__ xb, const bf16_t* __restrict__ Wb,
    bf16_t* __restrict__ Vt)
{
    __shared__ __align__(16) bf16_t As[BM * BK];
    __shared__ __align__(16) bf16_t Bs[BN * BK];
    const int lin = blockIdx.x;
    const int xcd = lin & 7;
    const int j   = lin >> 3;
    const int mblk = xcd * 8 + (j >> 3);
    const int nblk = j & 7;
    gemm_body<4>(As, Bs, xb, 1024, Wb, 1024, Vt, 2048,
                 0, 1024, 1.0f, mblk * BM, 2048 + nblk * BN, nullptr);
}

__global__ __launch_bounds__(256) void qk_gemm(
    const bf16_t* __restrict__ QKVb, bf16_t* __restrict__ E,
    float* __restrict__ rowsum)
{
    __shared__ __align__(16) bf16_t As[BM * BK];
    __shared__ __align__(16) bf16_t Bs[BN * BK];
    int b, my, nx;
    qk_tile(blockIdx.x, b, my, nx);
    const bf16_t* base = QKVb + (size_t)b * (2048L * 2048);
    gemm_body<3>(As, Bs,
                 base + 1024, 2048,
                 base, 2048,
                 E + (size_t)b * (2048L * 2048), 2048,
                 0, 1024, 0.03125f, my * BM, nx * BN,
                 rowsum + b * 2048);
}

// ---------------------------------------------------------------------------
// Kernel 4: out = (E * Vt^T) / rowsum per batch -> f32. tri-K (Keff=m0+128),
// grid 512, complementary-pair strip order (r7: neutral vs heavy-first, kept).
// ---------------------------------------------------------------------------
__global__ __launch_bounds__(256) void gemm3_pv(
    const bf16_t* __restrict__ E, const bf16_t* __restrict__ Vt,
    const float* __restrict__ rowsum, float* __restrict__ out)
{
    __shared__ __align__(16) bf16_t As[BM * BK];
    __shared__ __align__(16) bf16_t Bs[BN * BK];
    const int id = blockIdx.x;             // 0..511
    const int strip = (id < 256) ? (15 - (id >> 5)) : ((id - 256) >> 5);
    const int nx = (id >> 2) & 7;
    const int b = id & 3;
    const int m0 = strip * BM;
    gemm_body<2>(As, Bs,
                 E + (size_t)b * (2048L * 2048), 2048,
                 Vt + (size_t)b * (1024L * 2048), 2048,
                 out + (size_t)b * (2048L * 1024), 1024,
                 0, m0 + BM, 1.0f, m0, nx * BN,
                 (float*)rowsum + b * 2048);
}

// ---------------------------------------------------------------------------
extern "C" void kernel_launch(void* const* d_in, const int* in_sizes, int n_in,
                              void* d_out, int out_size, void* d_ws, size_t ws_size,
                              hipStream_t stream)
{
    const float* x  = (const float*)d_in[0];
    const float* Wk = (const float*)d_in[1];
    const float* Wq = (const float*)d_in[2];
    const float* Wv = (const float*)d_in[3];
    char* ws = (char*)d_ws;

    // ws layout:
    //   [0,32)    QKVb bf16 8192x2048  ([K|Q] columns; V goes to Vt)
    //   [32,48)   Vt   bf16 4 x 1024x2048 (written transposed)
    //   [48,64)   xb   bf16 8192x1024
    //   [64,70)   Wb   bf16 3072x1024
    // big-ws (>=107 MB): E at [72,105.6) NON-ALIASED (enables v+qk fusion),
    //   rowsum at [106,...). small-ws fallback: E aliases xb+Wb at [48,80),
    //   rowsum at [80,...), v/qk serialized.
    bf16_t* QKVb = (bf16_t*)(ws);
    bf16_t* Vt   = (bf16_t*)(ws + ((size_t)32 << 20));
    bf16_t* xb   = (bf16_t*)(ws + ((size_t)48 << 20));
    bf16_t* Wb   = (bf16_t*)(ws + ((size_t)64 << 20));
    const bool big = ws_size >= ((size_t)107 << 20);
    bf16_t* E      = (bf16_t*)(ws + ((size_t)(big ? 72 : 48) << 20));
    float*  rowsum = (float*)(ws + ((size_t)(big ? 106 : 80) << 20));
    float*  out    = (float*)d_out;

    // 1. cast inputs to bf16 + zero rowsum
    cast_all<<<11272, 256, 0, stream>>>(x, Wk, Wq, Wv, xb, Wb, rowsum);

    // 2. GEMM1 K|Q
    gemm1_kq128<<<1024, 256, 0, stream>>>(xb, Wb, QKVb);

    // 3. V-projection + causal exp(QK^T) fused (or serial fallback)
    if (big) {
        vqk_fused<<<1056, 256, 0, stream>>>(xb, Wb, Vt, QKVb, E, rowsum);
    } else {
        gemm1_v<<<512, 256, 0, stream>>>(xb, Wb, Vt);
        qk_gemm<<<544, 256, 0, stream>>>(QKVb, E, rowsum);
    }

    // 4. GEMM3: out = (E Vt^T)/rowsum, tri-K
    gemm3_pv<<<512, 256, 0, stream>>>(E, Vt, rowsum, out);
}

// Round 11
// 221.221 us; speedup vs baseline: 1.0593x; 1.0593x over previous
//
#include <hip/hip_runtime.h>
#include <hip/hip_bf16.h>
#include <hip/hip_fp16.h>
#include <stdint.h>

typedef __bf16 bf16_t;
typedef bf16_t bf16x8 __attribute__((ext_vector_type(8)));
typedef bf16_t bf16x4 __attribute__((ext_vector_type(4)));
typedef float f32x4 __attribute__((ext_vector_type(4)));

#define BM 128
#define BN 128
#define BK 64

// async global->LDS, 16B per lane. LDS dst is wave-uniform base + lane*16;
// the GLOBAL source may be arbitrary per-lane (used for the bank swizzle).
__device__ __forceinline__ void gload_lds16(const void* g, void* l) {
    __builtin_amdgcn_global_load_lds(
        (const __attribute__((address_space(1))) void*)(uintptr_t)g,
        (__attribute__((address_space(3))) void*)(uintptr_t)l,
        16, 0, 0);
}

// ---------------------------------------------------------------------------
// 128x128 body, BK=64 as TWO stacked BK=32 sub-tiles (r5: conflicts 4.3M->0).
// EPI: 2 = f32 store / rs[row]                  (gemm3)
//      3 = exp+causal bf16 store + atomic row-sum into rs  (qk)
//      4 = bf16 transposed into Vt[b][d][s]     (gemm1 V)
// CLOSED BRANCHES (do not revisit):
//  r6: per-tile agent fences -> L2 invalidation storm (FETCH 344 MB, 922 us)
//  r8: coop + __launch_bounds__(256,4) -> VGPR=64 spill storm (560 us)
//  r9: coop + free VGPR -> co-residency caps TLP + grid-stride kills XCD
//      L2 locality (FETCH 151 MB, 387 us)
//  r10: kq on 128^2 body -> +12 us vs 256^2 8-phase kq (234 vs 222)
// ---------------------------------------------------------------------------
template <int EPI>
__device__ __forceinline__ void gemm_body(
    bf16_t* __restrict__ As, bf16_t* __restrict__ Bs,
    const bf16_t* __restrict__ A, long lda,
    const bf16_t* __restrict__ B, long ldb,
    void* __restrict__ Cv, long ldc,
    int k0beg, int k1end, float scale, int m0, int n0,
    float* __restrict__ rs)
{
    const int tid = threadIdx.x;
    const int wid = tid >> 6, lane = tid & 63;
    const int wr = wid >> 1, wc = wid & 1;
    const int hw = lane >> 4, ln = lane & 15;

    const int row0 = tid >> 2;                       // 0..63
    const int jj = ((tid & 3) - (tid >> 3)) & 3;     // swizzle-compensated chunk
    const bf16_t* srcA0 = A + (size_t)(m0 + row0) * lda + jj * 8;
    const bf16_t* srcB0 = B + (size_t)(n0 + row0) * ldb + jj * 8;

    f32x4 acc[4][4] = {};

    for (int k0 = k0beg; k0 < k1end; k0 += BK) {
#pragma unroll
        for (int i = 0; i < 4; i++) {
            const size_t roff = (size_t)((i & 1) * 64);
            const int koff = k0 + (i >> 1) * 32;
            gload_lds16(srcA0 + roff * lda + koff, &As[i * 2048 + tid * 8]);
            gload_lds16(srcB0 + roff * ldb + koff, &Bs[i * 2048 + tid * 8]);
        }
        __syncthreads();

#pragma unroll
        for (int h = 0; h < 2; h++) {
            bf16x8 af[4], bfr[4];
#pragma unroll
            for (int t = 0; t < 4; t++) {
                const int r  = wr * 64 + t * 16 + ln;
                const int rb = wc * 64 + t * 16 + ln;
                af[t]  = *(const bf16x8*)&As[h * 4096 + r  * 32 + (((hw + (r  >> 1)) & 3) * 8)];
                bfr[t] = *(const bf16x8*)&Bs[h * 4096 + rb * 32 + (((hw + (rb >> 1)) & 3) * 8)];
            }
#pragma unroll
            for (int ti = 0; ti < 4; ti++)
#pragma unroll
                for (int tj = 0; tj < 4; tj++)
                    acc[ti][tj] = __builtin_amdgcn_mfma_f32_16x16x32_bf16(
                        af[ti], bfr[tj], acc[ti][tj], 0, 0, 0);
        }
        __syncthreads();
    }

    // epilogue: C/D layout col=lane&15, row=(lane>>4)*4+reg (m89-verified)
#pragma unroll
    for (int ti = 0; ti < 4; ti++) {
        const int rbase = m0 + wr * 64 + ti * 16 + hw * 4;
        f32x4 inv4;
        if (EPI == 2) {
            const float4 r4 = *(const float4*)&rs[rbase];
            inv4[0] = 1.0f / r4.x; inv4[1] = 1.0f / r4.y;
            inv4[2] = 1.0f / r4.z; inv4[3] = 1.0f / r4.w;
        }
        float part[4] = {0.f, 0.f, 0.f, 0.f};
#pragma unroll
        for (int tj = 0; tj < 4; tj++) {
            const int col = n0 + wc * 64 + tj * 16 + ln;
            if (EPI == 4) {
                // transposed bf16: 4 consecutive rows -> 8B contiguous in Vt
                const int bb = rbase >> 11;
                const int s  = rbase & 2047;
                const int d  = col - 2048;
                bf16x4 o;
#pragma unroll
                for (int rg = 0; rg < 4; rg++) o[rg] = (bf16_t)acc[ti][tj][rg];
                *(bf16x4*)&((bf16_t*)Cv)[(size_t)bb * 2097152 + (size_t)d * 2048 + s] = o;
            } else {
#pragma unroll
                for (int rg = 0; rg < 4; rg++) {
                    const size_t idx = (size_t)(rbase + rg) * ldc + col;
                    if (EPI == 2) {
                        ((float*)Cv)[idx] = acc[ti][tj][rg] * inv4[rg];
                    } else {  // EPI 3: exp + causal mask + row-sum
                        const float e = (col <= rbase + rg)
                                      ? __expf(acc[ti][tj][rg] * scale) : 0.0f;
                        part[rg] += e;
                        ((bf16_t*)Cv)[idx] = (bf16_t)e;
                    }
                }
            }
        }
        if (EPI == 3) {
#pragma unroll
            for (int rg = 0; rg < 4; rg++) {
                float p = part[rg];
                p += __shfl_xor(p, 1, 64);
                p += __shfl_xor(p, 2, 64);
                p += __shfl_xor(p, 4, 64);
                p += __shfl_xor(p, 8, 64);
                if (ln == 0) atomicAdd(&rs[rbase + rg], p);
            }
        }
    }
}

// ---------------------------------------------------------------------------
// 256x256 8-phase body for gemm1 K|Q (r5/r7-verified: kq ~44 us, total 222;
// r10 showed the 128^2 kq costs +12 us — keep THIS body for kq).
// ---------------------------------------------------------------------------
__device__ __forceinline__ void gemm256_body(
    bf16_t* __restrict__ lds,
    const bf16_t* __restrict__ A, long lda,
    const bf16_t* __restrict__ B, long ldb,
    bf16_t* __restrict__ C, long ldc,
    int nt, int m0, int n0)
{
    const int tid = threadIdx.x;
    const int wid = tid >> 6, lane = tid & 63;
    const int wr = wid >> 2, wcn = wid & 3;
    const int hw = lane >> 4, ln = lane & 15;

    const int srow = (wid << 3) + (lane >> 3);          // 0..63
    const int clog = ((lane & 7) - (lane >> 3)) & 7;    // swizzle-compensated chunk
    const bf16_t* sA = A + (size_t)(m0 + srow) * lda + clog * 8;
    const bf16_t* sB = B + (size_t)(n0 + srow) * ldb + clog * 8;
    char* ldsc = (char*)lds;
    const int wb = wid << 10;

#define STG_A(bf, q, kt) gload_lds16(sA + (size_t)(q) * 64 * lda + (size_t)(kt) * 64, \
                                     ldsc + (bf) * 65536 + (q) * 8192 + wb)
#define STG_B(bf, q, kt) gload_lds16(sB + (size_t)(q) * 64 * ldb + (size_t)(kt) * 64, \
                                     ldsc + (bf) * 65536 + 32768 + (q) * 8192 + wb)

    const int c0 = ((hw + ln) & 7) << 4;
    const int c1 = ((hw + ln + 4) & 7) << 4;
    const int aR = (wr * 128 + ln) * 128;
    const int bR = 32768 + (wcn * 64 + ln) * 128;

#define RDA(bf, fr, ks) (*(const bf16x8*)(ldsc + (bf) * 65536 + aR + (fr) * 2048 + ((ks) ? c1 : c0)))
#define RDB(bf, fc, ks) (*(const bf16x8*)(ldsc + (bf) * 65536 + bR + (fc) * 2048 + ((ks) ? c1 : c0)))

    f32x4 acc[8][4] = {};

    STG_A(0, 0, 0); STG_A(0, 2, 0); STG_B(0, 0, 0); STG_B(0, 1, 0);
    STG_A(0, 1, 0); STG_A(0, 3, 0); STG_B(0, 2, 0); STG_B(0, 3, 0);
    STG_A(1, 0, 1); STG_A(1, 2, 1); STG_B(1, 0, 1); STG_B(1, 1, 1);
    STG_A(1, 1, 1); STG_A(1, 3, 1);
    asm volatile("s_waitcnt vmcnt(6)" ::: "memory");
    __builtin_amdgcn_s_barrier();

    for (int t = 0; t < nt; ++t) {
        const int bc = t & 1, bn = bc ^ 1;
        const int kt1 = (t + 1) & (nt - 1);
        const int kt2 = (t + 2) & (nt - 1);
        bf16x8 af[4][2], bl[2][2], bh[2][2];

        // ---- P1
#pragma unroll
        for (int fr = 0; fr < 4; ++fr) {
            af[fr][0] = RDA(bc, fr, 0);
            af[fr][1] = RDA(bc, fr, 1);
        }
#pragma unroll
        for (int fc = 0; fc < 2; ++fc) {
            bl[fc][0] = RDB(bc, fc, 0);
            bl[fc][1] = RDB(bc, fc, 1);
        }
        STG_B(bn, 2, kt1); STG_B(bn, 3, kt1);
        __builtin_amdgcn_s_barrier();
        asm volatile("s_waitcnt lgkmcnt(0)" ::: "memory");
        __builtin_amdgcn_sched_barrier(0);
        __builtin_amdgcn_s_setprio(1);
#pragma unroll
        for (int fr = 0; fr < 4; ++fr)
#pragma unroll
            for (int fc = 0; fc < 2; ++fc)
#pragma unroll
                for (int ks = 0; ks < 2; ++ks)
                    acc[fr][fc] = __builtin_amdgcn_mfma_f32_16x16x32_bf16(
                        af[fr][ks], bl[fc][ks], acc[fr][fc], 0, 0, 0);
        __builtin_amdgcn_s_setprio(0);
        __builtin_amdgcn_s_barrier();

        // ---- P2
#pragma unroll
        for (int fc = 0; fc < 2; ++fc) {
            bh[fc][0] = RDB(bc, fc + 2, 0);
            bh[fc][1] = RDB(bc, fc + 2, 1);
        }
        STG_A(bc, 0, kt2); STG_A(bc, 2, kt2);
        __builtin_amdgcn_s_barrier();
        asm volatile("s_waitcnt lgkmcnt(0)" ::: "memory");
        __builtin_amdgcn_sched_barrier(0);
        __builtin_amdgcn_s_setprio(1);
#pragma unroll
        for (int fr = 0; fr < 4; ++fr)
#pragma unroll
            for (int fc = 0; fc < 2; ++fc)
#pragma unroll
                for (int ks = 0; ks < 2; ++ks)
                    acc[fr][fc + 2] = __builtin_amdgcn_mfma_f32_16x16x32_bf16(
                        af[fr][ks], bh[fc][ks], acc[fr][fc + 2], 0, 0, 0);
        __builtin_amdgcn_s_setprio(0);
        __builtin_amdgcn_s_barrier();

        // ---- P3
#pragma unroll
        for (int fr = 0; fr < 4; ++fr) {
            af[fr][0] = RDA(bc, fr + 4, 0);
            af[fr][1] = RDA(bc, fr + 4, 1);
        }
        STG_B(bc, 0, kt2); STG_B(bc, 1, kt2);
        __builtin_amdgcn_s_barrier();
        asm volatile("s_waitcnt lgkmcnt(0)" ::: "memory");
        __builtin_amdgcn_sched_barrier(0);
        __builtin_amdgcn_s_setprio(1);
#pragma unroll
        for (int fr = 0; fr < 4; ++fr)
#pragma unroll
            for (int fc = 0; fc < 2; ++fc)
#pragma unroll
                for (int ks = 0; ks < 2; ++ks)
                    acc[fr + 4][fc + 2] = __builtin_amdgcn_mfma_f32_16x16x32_bf16(
                        af[fr][ks], bh[fc][ks], acc[fr + 4][fc + 2], 0, 0, 0);
        __builtin_amdgcn_s_setprio(0);
        __builtin_amdgcn_s_barrier();

        // ---- P4
        STG_A(bc, 1, kt2); STG_A(bc, 3, kt2);
        __builtin_amdgcn_s_setprio(1);
#pragma unroll
        for (int fr = 0; fr < 4; ++fr)
#pragma unroll
            for (int fc = 0; fc < 2; ++fc)
#pragma unroll
                for (int ks = 0; ks < 2; ++ks)
                    acc[fr + 4][fc] = __builtin_amdgcn_mfma_f32_16x16x32_bf16(
                        af[fr][ks], bl[fc][ks], acc[fr + 4][fc], 0, 0, 0);
        __builtin_amdgcn_s_setprio(0);
        asm volatile("s_waitcnt vmcnt(6)" ::: "memory");
        __builtin_amdgcn_s_barrier();
    }

    asm volatile("s_waitcnt vmcnt(0)" ::: "memory");

#pragma unroll
    for (int fr = 0; fr < 8; ++fr) {
        const int rbase = m0 + wr * 128 + fr * 16 + hw * 4;
#pragma unroll
        for (int fc = 0; fc < 4; ++fc) {
            const int col = n0 + wcn * 64 + fc * 16 + ln;
#pragma unroll
            for (int rg = 0; rg < 4; rg++)
                C[(size_t)(rbase + rg) * ldc + col] = (bf16_t)acc[fr][fc][rg];
        }
    }
#undef STG_A
#undef STG_B
#undef RDA
#undef RDB
}

// ------------------------- shared tile-mapping helpers ---------------------
__device__ __forceinline__ void qk_tile(int q, int& b, int& my, int& nx) {
    b = q & 3;
    int rem = q >> 2;                      // 0..135
    my = 15; nx = 0;
#pragma unroll
    for (int m = 15; m >= 0; --m) {        // heavy strips first
        if (rem < m + 1) { my = m; nx = rem; break; }
        rem -= m + 1;
    }
}

// ---------------------------------------------------------------------------
// Kernel 1: merged input casts, grid-stride over 2048 blocks (G11; r11).
// units [0,8192) cast x, [8192,11264) cast W, [11264,11272) zero rowsum.
// ---------------------------------------------------------------------------
__global__ __launch_bounds__(256) void cast_all(
    const float* __restrict__ x,
    const float* __restrict__ Wk, const float* __restrict__ Wq,
    const float* __restrict__ Wv,
    bf16_t* __restrict__ xb, bf16_t* __restrict__ Wb,
    float* __restrict__ rowsum)
{
    for (int u = blockIdx.x; u < 11272; u += gridDim.x) {
        if (u >= 11264) {
            const size_t i = ((size_t)(u - 11264) * 256 + threadIdx.x) * 4;
            *(float4*)(rowsum + i) = make_float4(0.f, 0.f, 0.f, 0.f);
            continue;
        }
        const float* src;
        bf16_t* dst;
        if (u < 8192) {
            const size_t i = ((size_t)u * 256 + threadIdx.x) * 4;
            src = x + i;
            dst = xb + i;
        } else {
            const size_t j = ((size_t)(u - 8192) * 256 + threadIdx.x) * 4;
            dst = Wb + j;
            if (j < (size_t)1048576)      src = Wk + j;
            else if (j < (size_t)2097152) src = Wq + (j - 1048576);
            else                          src = Wv + (j - 2097152);
        }
        const float4 v = *(const float4*)src;
        bf16x4 o;
        o.x = (bf16_t)v.x; o.y = (bf16_t)v.y; o.z = (bf16_t)v.z; o.w = (bf16_t)v.w;
        *(bf16x4*)dst = o;
    }
}

// ---------------------------------------------------------------------------
// Kernel 2: [K|Q] = x*W^T into QKVb (8192x2048). 256^2 8-phase body,
// grid EXACTLY 256 (one clean round, 1 block/CU). XCD: xcd owns mblk [4x,4x+4).
// ---------------------------------------------------------------------------
__global__ __launch_bounds__(512, 2) void gemm1_kq(
    const bf16_t* __restrict__ xb, const bf16_t* __restrict__ Wb,
    bf16_t* __restrict__ QKVb)
{
    __shared__ __align__(16) bf16_t lds[65536];   // 128 KiB
    const int lin = blockIdx.x;                   // 0..255
    const int xcd = lin & 7;
    const int j   = lin >> 3;                     // 0..31
    const int mblk = xcd * 4 + (j & 3);           // 0..31
    const int nblk = j >> 2;                      // 0..7
    gemm256_body(lds, xb, 1024, Wb, 1024, QKVb, 2048, 16, mblk * 256, nblk * 256);
}

// ---------------------------------------------------------------------------
// Kernel 3: FUSED V-projection + QK-exp (independent once kq is done).
// ids [0,512)=V transposed into Vt; [512,1056)=QK heavy-first.
// ---------------------------------------------------------------------------
__global__ __launch_bounds__(256) void vqk_fused(
    const bf16_t* __restrict__ xb, const bf16_t* __restrict__ Wb,
    bf16_t* __restrict__ Vt,
    const bf16_t* __restrict__ QKVb, bf16_t* __restrict__ E,
    float* __restrict__ rowsum)
{
    __shared__ __align__(16) bf16_t As[BM * BK];
    __shared__ __align__(16) bf16_t Bs[BN * BK];
    const int id = blockIdx.x;
    if (id < 512) {
        const int xcd = id & 7;
        const int j   = id >> 3;               // 0..63
        const int mblk = xcd * 8 + (j >> 3);   // 0..63
        const int nblk = j & 7;                // 0..7
        gemm_body<4>(As, Bs, xb, 1024, Wb, 1024, Vt, 2048,
                     0, 1024, 1.0f, mblk * BM, 2048 + nblk * BN, nullptr);
    } else {
        int b, my, nx;
        qk_tile(id - 512, b, my, nx);
        const bf16_t* base = QKVb + (size_t)b * (2048L * 2048);
        gemm_body<3>(As, Bs,
                     base + 1024, 2048,        // Q
                     base, 2048,               // K
                     E + (size_t)b * (2048L * 2048), 2048,
                     0, 1024, 0.03125f, my * BM, nx * BN,
                     rowsum + b * 2048);
    }
}

// --------------------- serial pair (small-ws fallback) ---------------------
__global__ __launch_bounds__(256) void gemm1_v(
    const bf16_t* __restrict__ xb, const bf16_t* __restrict__ Wb,
    bf16_t* __restrict__ Vt)
{
    __shared__ __align__(16) bf16_t As[BM * BK];
    __shared__ __align__(16) bf16_t Bs[BN * BK];
    const int lin = blockIdx.x;
    const int xcd = lin & 7;
    const int j   = lin >> 3;
    const int mblk = xcd * 8 + (j >> 3);
    const int nblk = j & 7;
    gemm_body<4>(As, Bs, xb, 1024, Wb, 1024, Vt, 2048,
                 0, 1024, 1.0f, mblk * BM, 2048 + nblk * BN, nullptr);
}

__global__ __launch_bounds__(256) void qk_gemm(
    const bf16_t* __restrict__ QKVb, bf16_t* __restrict__ E,
    float* __restrict__ rowsum)
{
    __shared__ __align__(16) bf16_t As[BM * BK];
    __shared__ __align__(16) bf16_t Bs[BN * BK];
    int b, my, nx;
    qk_tile(blockIdx.x, b, my, nx);
    const bf16_t* base = QKVb + (size_t)b * (2048L * 2048);
    gemm_body<3>(As, Bs,
                 base + 1024, 2048,
                 base, 2048,
                 E + (size_t)b * (2048L * 2048), 2048,
                 0, 1024, 0.03125f, my * BM, nx * BN,
                 rowsum + b * 2048);
}

// ---------------------------------------------------------------------------
// Kernel 4: out = (E * Vt^T) / rowsum per batch -> f32. tri-K (Keff=m0+128),
// grid 512, complementary-pair strip order.
// ---------------------------------------------------------------------------
__global__ __launch_bounds__(256) void gemm3_pv(
    const bf16_t* __restrict__ E, const bf16_t* __restrict__ Vt,
    const float* __restrict__ rowsum, float* __restrict__ out)
{
    __shared__ __align__(16) bf16_t As[BM * BK];
    __shared__ __align__(16) bf16_t Bs[BN * BK];
    const int id = blockIdx.x;             // 0..511
    const int strip = (id < 256) ? (15 - (id >> 5)) : ((id - 256) >> 5);
    const int nx = (id >> 2) & 7;
    const int b = id & 3;
    const int m0 = strip * BM;
    gemm_body<2>(As, Bs,
                 E + (size_t)b * (2048L * 2048), 2048,
                 Vt + (size_t)b * (1024L * 2048), 2048,
                 out + (size_t)b * (2048L * 1024), 1024,
                 0, m0 + BM, 1.0f, m0, nx * BN,
                 (float*)rowsum + b * 2048);
}

// ---------------------------------------------------------------------------
extern "C" void kernel_launch(void* const* d_in, const int* in_sizes, int n_in,
                              void* d_out, int out_size, void* d_ws, size_t ws_size,
                              hipStream_t stream)
{
    const float* x  = (const float*)d_in[0];
    const float* Wk = (const float*)d_in[1];
    const float* Wq = (const float*)d_in[2];
    const float* Wv = (const float*)d_in[3];
    char* ws = (char*)d_ws;

    // ws layout:
    //   [0,32)    QKVb bf16 8192x2048  ([K|Q] columns; V goes to Vt)
    //   [32,48)   Vt   bf16 4 x 1024x2048 (written transposed)
    //   [48,64)   xb   bf16 8192x1024
    //   [64,70)   Wb   bf16 3072x1024
    // big-ws (>=107 MB): E at [72,105.6) NON-ALIASED (enables v+qk fusion),
    //   rowsum at [106,...). small-ws fallback: E aliases xb+Wb at [48,80),
    //   rowsum at [80,...), v/qk serialized.
    bf16_t* QKVb = (bf16_t*)(ws);
    bf16_t* Vt   = (bf16_t*)(ws + ((size_t)32 << 20));
    bf16_t* xb   = (bf16_t*)(ws + ((size_t)48 << 20));
    bf16_t* Wb   = (bf16_t*)(ws + ((size_t)64 << 20));
    const bool big = ws_size >= ((size_t)107 << 20);
    bf16_t* E      = (bf16_t*)(ws + ((size_t)(big ? 72 : 48) << 20));
    float*  rowsum = (float*)(ws + ((size_t)(big ? 106 : 80) << 20));
    float*  out    = (float*)d_out;

    // 1. cast inputs to bf16 + zero rowsum (grid-stride, 2048 blocks)
    cast_all<<<2048, 256, 0, stream>>>(x, Wk, Wq, Wv, xb, Wb, rowsum);

    // 2. GEMM1 K|Q: 256^2 8-phase body, exactly 256 blocks
    gemm1_kq<<<256, 512, 0, stream>>>(xb, Wb, QKVb);

    // 3. V-projection + causal exp(QK^T) fused (or serial fallback)
    if (big) {
        vqk_fused<<<1056, 256, 0, stream>>>(xb, Wb, Vt, QKVb, E, rowsum);
    } else {
        gemm1_v<<<512, 256, 0, stream>>>(xb, Wb, Vt);
        qk_gemm<<<544, 256, 0, stream>>>(QKVb, E, rowsum);
    }

    // 4. GEMM3: out = (E Vt^T)/rowsum, tri-K
    gemm3_pv<<<512, 256, 0, stream>>>(E, Vt, rowsum, out);
}